// Round 12
// baseline (370.992 us; speedup 1.0000x reference)
//
#include <hip/hip_runtime.h>
#include <hip/hip_cooperative_groups.h>
#include <math.h>

namespace cg = cooperative_groups;

#define N_NODES 100000
#define DIM 64
#define N_EDGES 1250000
#define SCAN_BLOCKS 256
#define RPB 128                                   // rows per bucket (row>>7)
#define NB_BUCKETS ((N_NODES + RPB - 1) / RPB)    // 782
#define NBLK_B 128                                // blocks in hist/scatter phase
#define CNT_N (NB_BUCKETS * NBLK_B)               // 100096 = 391*256
#define CAP 2048                                  // max edges per bucket (mean 1600)
#define BGRID 512                                 // cooperative build grid

typedef unsigned short ushort_t;
typedef unsigned int uint_t;
typedef _Float16 h2 __attribute__((ext_vector_type(2)));

// fp16 (storage) <-> f32 (compute) helpers
__device__ __forceinline__ float hlo(uint_t u) {
    return (float)__builtin_bit_cast(_Float16, (ushort_t)(u & 0xFFFFu));
}
__device__ __forceinline__ float hhi(uint_t u) {
    return (float)__builtin_bit_cast(_Float16, (ushort_t)(u >> 16));
}
__device__ __forceinline__ uint_t f2h(float f) {   // RTNE via v_cvt_f16_f32
    return (uint_t)__builtin_bit_cast(ushort_t, (_Float16)f);
}

// acc two fp16 lanes of a dword into two f32 accumulators via v_dot2_f32_f16
__device__ __forceinline__ void dacc(float& a0, float& a1, uint_t u) {
#if __has_builtin(__builtin_amdgcn_fdot2)
    h2 h = __builtin_bit_cast(h2, u);
    const h2 e0 = {(_Float16)1.0f, (_Float16)0.0f};
    const h2 e1 = {(_Float16)0.0f, (_Float16)1.0f};
    a0 = __builtin_amdgcn_fdot2(h, e0, a0, false);
    a1 = __builtin_amdgcn_fdot2(h, e1, a1, false);
#else
    a0 += hlo(u);
    a1 += hhi(u);
#endif
}

__device__ __forceinline__ void dacc4(float* acc, uint4 v) {
    dacc(acc[0], acc[1], v.x); dacc(acc[2], acc[3], v.y);
    dacc(acc[4], acc[5], v.z); dacc(acc[6], acc[7], v.w);
}

// ---- LDS phase union for the fused build kernel (max ~17.9 KB) ------------
struct CsrShared { int pk[CAP]; int csr[CAP]; int deg[RPB]; int scn[RPB]; int cur[RPB]; };
union BuildShared {
    int h[NB_BUCKETS];     // hist counts / scatter cursors (782)
    int sh[SCAN_BLOCKS];   // scan tiles (256)
    CsrShared c;           // bucket-CSR phase
};

// ============================================================================
// ONE cooperative kernel for the whole CSR build (was 6 kernels):
//   A: blocks[0,128) bucket histogram -> cnt (bucket-major);
//      blocks[128,512) emb f32 -> fp16 conversion
//   B1: blocks[0,256) per-chunk partial sums of cnt
//   B2: blocks[0,256) redundant 256-wide blocksum scan + tile-scan emit of
//       slot_off (kills the old single-block scan_small launch)
//   C: blocks[0,128) scatter packed edges into per-(bucket,block) slots
//   D: grid-stride over 782 buckets: LDS histogram/scan/place -> row_ptr,
//      dis, csr_col (byte offsets), contiguous stream-out
// grid.sync() between phases replaces kernel-boundary drain gaps.
// ============================================================================
__global__ void __launch_bounds__(256) build_kernel(
        const float* __restrict__ emb, ushort_t* __restrict__ embh,
        const int* __restrict__ row, const int* __restrict__ col,
        int* __restrict__ cnt, int* __restrict__ blocksum,
        int* __restrict__ slot_off, int* __restrict__ pairs,
        int* __restrict__ row_ptr, float* __restrict__ dis,
        int* __restrict__ csr_col) {
    cg::grid_group grid = cg::this_grid();
    __shared__ BuildShared S;
    int t = threadIdx.x;
    int blk = blockIdx.x;
    const int n8 = N_NODES * DIM / 8;
    const int chunk = (CNT_N + SCAN_BLOCKS - 1) / SCAN_BLOCKS;   // 391

    // ---- Phase A: histogram + conv ----
    if (blk < NBLK_B) {
        for (int i = t; i < NB_BUCKETS; i += 256) S.h[i] = 0;
        __syncthreads();
        int per = (N_EDGES + NBLK_B - 1) / NBLK_B;
        int lo = blk * per, hi = min(lo + per, N_EDGES);
        for (int e = lo + t; e < hi; e += 256)
            atomicAdd(&S.h[row[e] >> 7], 1);
        __syncthreads();
        for (int b = t; b < NB_BUCKETS; b += 256)
            cnt[b * NBLK_B + blk] = S.h[b];   // bucket-major
    } else {
        const int nconv = BGRID - NBLK_B;     // 384 conversion blocks
        for (int i = (blk - NBLK_B) * 256 + t; i < n8; i += nconv * 256) {
            float4 a = reinterpret_cast<const float4*>(emb)[2 * i];
            float4 b4 = reinterpret_cast<const float4*>(emb)[2 * i + 1];
            uint4 w;
            w.x = f2h(a.x) | (f2h(a.y) << 16);
            w.y = f2h(a.z) | (f2h(a.w) << 16);
            w.z = f2h(b4.x) | (f2h(b4.y) << 16);
            w.w = f2h(b4.z) | (f2h(b4.w) << 16);
            reinterpret_cast<uint4*>(embh)[i] = w;
        }
    }
    grid.sync();

    // ---- Phase B1: per-chunk partial sums ----
    if (blk < SCAN_BLOCKS) {
        int lo = blk * chunk, hi = min(lo + chunk, CNT_N);
        int s = 0;
        for (int i = lo + t; i < hi; i += 256) s += cnt[i];
        S.sh[t] = s;
        __syncthreads();
        for (int off = 128; off > 0; off >>= 1) {
            if (t < off) S.sh[t] += S.sh[t + off];
            __syncthreads();
        }
        if (t == 0) blocksum[blk] = S.sh[0];
    }
    grid.sync();

    // ---- Phase B2: redundant blocksum scan + emit slot_off ----
    if (blk < SCAN_BLOCKS) {
        int v = blocksum[t];
        S.sh[t] = v;
        __syncthreads();
        for (int off = 1; off < SCAN_BLOCKS; off <<= 1) {
            int u = (t >= off) ? S.sh[t - off] : 0;
            __syncthreads();
            S.sh[t] += u;
            __syncthreads();
        }
        int running = (blk > 0) ? S.sh[blk - 1] : 0;   // exclusive block base
        int total = S.sh[SCAN_BLOCKS - 1];
        __syncthreads();
        int lo = blk * chunk, hi = min(lo + chunk, CNT_N);
        for (int base = lo; base < hi; base += 256) {
            int i = base + t;
            int d = (i < hi) ? cnt[i] : 0;
            S.sh[t] = d;
            __syncthreads();
            for (int off = 1; off < 256; off <<= 1) {
                int u = (t >= off) ? S.sh[t - off] : 0;
                __syncthreads();
                S.sh[t] += u;
                __syncthreads();
            }
            if (i < hi) slot_off[i] = running + (S.sh[t] - d);
            running += S.sh[255];
            __syncthreads();
        }
        if (blk == 0 && t == 0) slot_off[CNT_N] = total;   // = E
    }
    grid.sync();

    // ---- Phase C: scatter packed edges ----
    if (blk < NBLK_B) {
        for (int b = t; b < NB_BUCKETS; b += 256)
            S.h[b] = slot_off[b * NBLK_B + blk];
        __syncthreads();
        int per = (N_EDGES + NBLK_B - 1) / NBLK_B;
        int lo = blk * per, hi = min(lo + per, N_EDGES);
        for (int e = lo + t; e < hi; e += 256) {
            int r = row[e], c = col[e];
            int pos = atomicAdd(&S.h[r >> 7], 1);
            pairs[pos] = ((r & (RPB - 1)) << 17) | c;
        }
    }
    grid.sync();

    // ---- Phase D: per-bucket CSR build (grid-stride over 782 buckets) ----
    for (int b = blk; b < NB_BUCKETS; b += BGRID) {
        int start = slot_off[b * NBLK_B];
        int end = slot_off[(b + 1) * NBLK_B];
        int cntb = end - start;
        bool fits = (cntb <= CAP);
        if (t < RPB) S.c.deg[t] = 0;
        if (fits) {
            for (int i = t; i < cntb; i += 256) S.c.pk[i] = pairs[start + i];
        }
        __syncthreads();
        for (int i = t; i < cntb; i += 256) {
            int p = fits ? S.c.pk[i] : pairs[start + i];
            atomicAdd(&S.c.deg[p >> 17], 1);
        }
        __syncthreads();
        int d = (t < RPB) ? S.c.deg[t] : 0;
        if (t < RPB) S.c.scn[t] = d;
        __syncthreads();
        for (int off = 1; off < RPB; off <<= 1) {
            int v2 = (t < RPB && t >= off) ? S.c.scn[t - off] : 0;
            __syncthreads();
            if (t < RPB) S.c.scn[t] += v2;
            __syncthreads();
        }
        if (t < RPB) {
            int exc = S.c.scn[t] - d;
            S.c.cur[t] = exc;
            int rg = b * RPB + t;
            if (rg < N_NODES) {
                row_ptr[rg] = start + exc;
                dis[rg] = (d > 0) ? (float)(1.0 / sqrt((double)d)) : 0.0f;
            }
        }
        __syncthreads();
        // place BYTE OFFSETS (col * DIM * 2 = col<<7) by row within the bucket
        for (int i = t; i < cntb; i += 256) {
            int p = fits ? S.c.pk[i] : pairs[start + i];
            int pos = atomicAdd(&S.c.cur[p >> 17], 1);
            int c = (p & 0x1FFFF) << 7;
            if (fits) S.c.csr[pos] = c;
            else      csr_col[start + pos] = c;
        }
        __syncthreads();
        if (fits) {
            for (int i = t; i < cntb; i += 256) csr_col[start + i] = S.c.csr[i];
        }
        if (b == NB_BUCKETS - 1 && t == 0) row_ptr[N_NODES] = N_EDGES;
        __syncthreads();   // protect LDS before next bucket iteration
    }
}

// Grid-stride, two nodes per wave (lanes 0-31 / 32-63). Within a node:
// 4 groups of 8 lanes; group g handles edges start+g, +4, ... Each group
// loads one full fp16 row (128B). Rotated software pipeline: csr offsets for
// iteration i+1 are loaded (branch-free, min-clamped) while iteration i's row
// loads are in flight. Normal cached loads for csr_col (64B line reused ~16x
// per wave -- round-10 lesson: never non-temporal). v_dot2_f32_f16 accumulate;
// cross-group reduce via shfl_xor(8,16).
// MODE 0/1: write x_new = fp16(acc * dis^2)
// MODE 2 (last layer, fused combine): out = 0.25*(embh + x1 + x2 + acc*dis^2)
template <int MODE>
__global__ void gather_kernel(const int* __restrict__ row_ptr, const int* __restrict__ csr_col,
                              const float* __restrict__ dis,
                              const ushort_t* __restrict__ x_old, ushort_t* __restrict__ x_new,
                              const ushort_t* __restrict__ e0, const ushort_t* __restrict__ x1,
                              const ushort_t* __restrict__ x2, float* __restrict__ out,
                              int Npair) {
    int lane = threadIdx.x & 63;
    int sub = lane >> 5;   // which node of the pair
    int l5 = lane & 31;
    int g = l5 >> 3;       // edge-group 0..3 within node
    int l = l5 & 7;        // lane within group: owns dims 8l..8l+7
    int lb = l * 16;       // lane byte offset within a 128B row
    const char* xb = (const char*)x_old;

    int wave0 = (int)((blockIdx.x * (size_t)blockDim.x + threadIdx.x) >> 6);
    int nwaves = (int)(((size_t)gridDim.x * blockDim.x) >> 6);

    for (int wid = wave0; wid < Npair; wid += nwaves) {
        int node = wid * 2 + sub;
        int start = row_ptr[node];
        int end = row_ptr[node + 1];

        float acc[8];
        #pragma unroll
        for (int k = 0; k < 8; ++k) acc[k] = 0.f;

        int e = start + g;
        if (e < end) {
            int o0 = csr_col[e];
            int o1 = (e + 4 < end) ? csr_col[e + 4] : 0;
            while (e + 4 < end) {
                uint4 v0 = *reinterpret_cast<const uint4*>(xb + o0 + lb);
                uint4 v1 = *reinterpret_cast<const uint4*>(xb + o1 + lb);
                o0 = csr_col[min(e + 8, N_EDGES - 1)];
                o1 = csr_col[min(e + 12, N_EDGES - 1)];
                dacc4(acc, v0); dacc4(acc, v1);
                e += 8;
            }
            if (e < end) {   // tail: o0 already holds csr_col[e]
                uint4 v0 = *reinterpret_cast<const uint4*>(xb + o0 + lb);
                dacc4(acc, v0);
            }
        }

        #pragma unroll
        for (int off = 8; off <= 16; off <<= 1) {
            #pragma unroll
            for (int k = 0; k < 8; ++k) acc[k] += __shfl_xor(acc[k], off, 64);
        }

        if (g == 0) {
            float s = dis[node];
            float s2 = s * s;
            if (MODE != 2) {
                uint4 w;
                w.x = f2h(acc[0] * s2) | (f2h(acc[1] * s2) << 16);
                w.y = f2h(acc[2] * s2) | (f2h(acc[3] * s2) << 16);
                w.z = f2h(acc[4] * s2) | (f2h(acc[5] * s2) << 16);
                w.w = f2h(acc[6] * s2) | (f2h(acc[7] * s2) << 16);
                *reinterpret_cast<uint4*>(&x_new[(size_t)node * DIM + l * 8]) = w;
            } else {
                size_t ob = (size_t)node * (DIM * 2) + lb;
                uint4 ea  = *reinterpret_cast<const uint4*>((const char*)e0 + ob);
                uint4 u1  = *reinterpret_cast<const uint4*>((const char*)x1 + ob);
                uint4 u2  = *reinterpret_cast<const uint4*>((const char*)x2 + ob);
                float4 r0, r1;
                r0.x = (hlo(ea.x) + hlo(u1.x) + hlo(u2.x) + acc[0] * s2) * 0.25f;
                r0.y = (hhi(ea.x) + hhi(u1.x) + hhi(u2.x) + acc[1] * s2) * 0.25f;
                r0.z = (hlo(ea.y) + hlo(u1.y) + hlo(u2.y) + acc[2] * s2) * 0.25f;
                r0.w = (hhi(ea.y) + hhi(u1.y) + hhi(u2.y) + acc[3] * s2) * 0.25f;
                r1.x = (hlo(ea.z) + hlo(u1.z) + hlo(u2.z) + acc[4] * s2) * 0.25f;
                r1.y = (hhi(ea.z) + hhi(u1.z) + hhi(u2.z) + acc[5] * s2) * 0.25f;
                r1.z = (hlo(ea.w) + hlo(u1.w) + hlo(u2.w) + acc[6] * s2) * 0.25f;
                r1.w = (hhi(ea.w) + hhi(u1.w) + hhi(u2.w) + acc[7] * s2) * 0.25f;
                size_t oo = (size_t)node * DIM + l * 8;
                *reinterpret_cast<float4*>(&out[oo]) = r0;
                *reinterpret_cast<float4*>(&out[oo + 4]) = r1;
            }
        }
    }
}

extern "C" void kernel_launch(void* const* d_in, const int* in_sizes, int n_in,
                              void* d_out, int out_size, void* d_ws, size_t ws_size,
                              hipStream_t stream) {
    const int* edge = (const int*)d_in[0];       // (2, E) int32
    const int* row = edge;
    const int* col = edge + N_EDGES;
    const float* emb = (const float*)d_in[1];    // (N, 64) f32
    float* out = (float*)d_out;                  // (N, 64) f32

    char* ws = (char*)d_ws;
    size_t off = 0;
    auto alloc = [&](size_t bytes) {
        char* p = ws + off;
        off += (bytes + 255) & ~(size_t)255;
        return p;
    };
    int*      row_ptr  = (int*)alloc(((size_t)N_NODES + 1) * sizeof(int));
    float*    dis      = (float*)alloc((size_t)N_NODES * sizeof(float));
    int*      blocksum = (int*)alloc((size_t)SCAN_BLOCKS * sizeof(int));
    int*      cnt      = (int*)alloc((size_t)CNT_N * sizeof(int));
    int*      slot_off = (int*)alloc(((size_t)CNT_N + 1) * sizeof(int));
    int*      csr_col  = (int*)alloc((size_t)N_EDGES * sizeof(int));
    ushort_t* embh     = (ushort_t*)alloc((size_t)N_NODES * DIM * sizeof(ushort_t));
    ushort_t* x1       = (ushort_t*)alloc((size_t)N_NODES * DIM * sizeof(ushort_t));
    ushort_t* x2       = (ushort_t*)alloc((size_t)N_NODES * DIM * sizeof(ushort_t));
    // pairs (5MB) aliases x2 (12.8MB): pairs dead after build_kernel,
    // x2 first written by the second gather (later) -> lifetimes disjoint.
    int*      pairs    = (int*)x2;

    const int gather_blocks = 2048;   // 8 blocks/CU, persistent grid-stride waves

    // ---- fused CSR build: ONE cooperative launch (was 6 kernels) ----
    void* args[] = {(void*)&emb, (void*)&embh, (void*)&row, (void*)&col,
                    (void*)&cnt, (void*)&blocksum, (void*)&slot_off, (void*)&pairs,
                    (void*)&row_ptr, (void*)&dis, (void*)&csr_col};
    hipLaunchCooperativeKernel((void*)build_kernel, dim3(BGRID), dim3(256),
                               args, 0, stream);

    // 3 propagate layers (fp16 storage, f32 accumulate via v_dot2_f32_f16);
    // layer 3 fuses the final combine: out = 0.25*(emb + x1 + x2 + x3)
    gather_kernel<0><<<gather_blocks, 256, 0, stream>>>(row_ptr, csr_col, dis, embh, x1,
                                                        nullptr, nullptr, nullptr, nullptr, N_NODES / 2);
    gather_kernel<1><<<gather_blocks, 256, 0, stream>>>(row_ptr, csr_col, dis, x1, x2,
                                                        nullptr, nullptr, nullptr, nullptr, N_NODES / 2);
    gather_kernel<2><<<gather_blocks, 256, 0, stream>>>(row_ptr, csr_col, dis, x2, nullptr,
                                                        embh, x1, x2, out, N_NODES / 2);
}

// Round 13
// 186.491 us; speedup vs baseline: 1.9893x; 1.9893x over previous
//
#include <hip/hip_runtime.h>
#include <math.h>

#define N_NODES 100000
#define DIM 64
#define N_EDGES 1250000
#define SCAN_BLOCKS 256
#define RPB 128                                   // rows per bucket (row>>7)
#define NB_BUCKETS ((N_NODES + RPB - 1) / RPB)    // 782
#define NBLK_B 128                                // blocks in hist/scatter pass
#define CNT_N (NB_BUCKETS * NBLK_B)               // 100096 = 391*256
#define CAP 2048                                  // max edges per bucket (mean 1600)

typedef unsigned short ushort_t;
typedef unsigned int uint_t;
typedef _Float16 h2 __attribute__((ext_vector_type(2)));

// fp16 (storage) <-> f32 (compute) helpers
__device__ __forceinline__ float hlo(uint_t u) {
    return (float)__builtin_bit_cast(_Float16, (ushort_t)(u & 0xFFFFu));
}
__device__ __forceinline__ float hhi(uint_t u) {
    return (float)__builtin_bit_cast(_Float16, (ushort_t)(u >> 16));
}
__device__ __forceinline__ uint_t f2h(float f) {   // RTNE via v_cvt_f16_f32
    return (uint_t)__builtin_bit_cast(ushort_t, (_Float16)f);
}

// acc two fp16 lanes of a dword into two f32 accumulators via v_dot2_f32_f16
__device__ __forceinline__ void dacc(float& a0, float& a1, uint_t u) {
#if __has_builtin(__builtin_amdgcn_fdot2)
    h2 h = __builtin_bit_cast(h2, u);
    const h2 e0 = {(_Float16)1.0f, (_Float16)0.0f};
    const h2 e1 = {(_Float16)0.0f, (_Float16)1.0f};
    a0 = __builtin_amdgcn_fdot2(h, e0, a0, false);
    a1 = __builtin_amdgcn_fdot2(h, e1, a1, false);
#else
    a0 += hlo(u);
    a1 += hhi(u);
#endif
}

__device__ __forceinline__ void dacc4(float* acc, uint4 v) {
    dacc(acc[0], acc[1], v.x); dacc(acc[2], acc[3], v.y);
    dacc(acc[4], acc[5], v.z); dacc(acc[6], acc[7], v.w);
}

// ---- fused: blocks [0,NBLK_B) = bucket histogram; rest = emb->fp16 conv ---
__global__ void conv_hist_kernel(const float* __restrict__ emb, ushort_t* __restrict__ embh,
                                 int n8, const int* __restrict__ row,
                                 int* __restrict__ cnt, int E) {
    __shared__ int h[NB_BUCKETS];
    if (blockIdx.x < NBLK_B) {
        for (int i = threadIdx.x; i < NB_BUCKETS; i += blockDim.x) h[i] = 0;
        __syncthreads();
        int blk = blockIdx.x;
        int per = (E + NBLK_B - 1) / NBLK_B;
        int lo = blk * per, hi = min(lo + per, E);
        for (int e = lo + (int)threadIdx.x; e < hi; e += blockDim.x)
            atomicAdd(&h[row[e] >> 7], 1);
        __syncthreads();
        for (int b = threadIdx.x; b < NB_BUCKETS; b += blockDim.x)
            cnt[b * NBLK_B + blk] = h[b];   // bucket-major: scan order = slot order
    } else {
        int i = (blockIdx.x - NBLK_B) * blockDim.x + threadIdx.x;
        if (i < n8) {
            float4 a = reinterpret_cast<const float4*>(emb)[2 * i];
            float4 b = reinterpret_cast<const float4*>(emb)[2 * i + 1];
            uint4 w;
            w.x = f2h(a.x) | (f2h(a.y) << 16);
            w.y = f2h(a.z) | (f2h(a.w) << 16);
            w.z = f2h(b.x) | (f2h(b.y) << 16);
            w.w = f2h(b.z) | (f2h(b.w) << 16);
            reinterpret_cast<uint4*>(embh)[i] = w;
        }
    }
}

// ---- ONE-kernel device-wide exclusive scan (redundant-scan idiom) ---------
// Replaces partial + scan_small + scan_emit (3 launches -> 1, no grid.sync).
// Every block independently computes all 256 chunk-partials (thread t sums
// chunk t: ~400KB of L2-hot cnt reads per block), LDS-scans them, takes its
// own exclusive base, then tile-scans its chunk and emits slot_off.
__global__ void __launch_bounds__(SCAN_BLOCKS) scan_fused_kernel(
        const int* __restrict__ cnt, int* __restrict__ slot_off, int N, int chunk) {
    __shared__ int sh[SCAN_BLOCKS];
    int t = threadIdx.x;
    int b = blockIdx.x;
    // thread t: partial sum of chunk t (sequential reads, L1-friendly)
    int lo = t * chunk, hi = min(lo + chunk, N);
    int s = 0;
    for (int i = lo; i < hi; ++i) s += cnt[i];
    sh[t] = s;
    __syncthreads();
    // inclusive Hillis-Steele over the 256 partials
    for (int off = 1; off < SCAN_BLOCKS; off <<= 1) {
        int u = (t >= off) ? sh[t - off] : 0;
        __syncthreads();
        sh[t] += u;
        __syncthreads();
    }
    int running = (b > 0) ? sh[b - 1] : 0;   // this block's exclusive base
    int total = sh[SCAN_BLOCKS - 1];
    __syncthreads();
    // tile-scan own chunk -> slot_off
    lo = b * chunk; hi = min(lo + chunk, N);
    for (int base = lo; base < hi; base += 256) {
        int i = base + t;
        int d = (i < hi) ? cnt[i] : 0;
        sh[t] = d;
        __syncthreads();
        for (int off = 1; off < 256; off <<= 1) {
            int u = (t >= off) ? sh[t - off] : 0;
            __syncthreads();
            sh[t] += u;
            __syncthreads();
        }
        if (i < hi) slot_off[i] = running + (sh[t] - d);
        running += sh[255];
        __syncthreads();
    }
    if (b == 0 && t == 0) slot_off[N] = total;   // = E
}

// ---- bucket pass 2: scatter packed edges into per-(bucket,block) slots ----
__global__ void bucket_scatter_kernel(const int* __restrict__ row, const int* __restrict__ col,
                                      const int* __restrict__ slot_off,
                                      int* __restrict__ pairs, int E) {
    __shared__ int cur[NB_BUCKETS];
    int blk = blockIdx.x;
    for (int b = threadIdx.x; b < NB_BUCKETS; b += blockDim.x)
        cur[b] = slot_off[b * NBLK_B + blk];
    __syncthreads();
    int per = (E + (int)gridDim.x - 1) / (int)gridDim.x;
    int lo = blk * per, hi = min(lo + per, E);
    for (int e = lo + (int)threadIdx.x; e < hi; e += blockDim.x) {
        int r = row[e], c = col[e];
        int pos = atomicAdd(&cur[r >> 7], 1);
        pairs[pos] = ((r & (RPB - 1)) << 17) | c;
    }
}

// ---- bucket pass 3: one block per bucket -> row_ptr, dis, csr (byte offs) --
__global__ void __launch_bounds__(256) bucket_csr_kernel(
        const int* __restrict__ slot_off, const int* __restrict__ pairs,
        int* __restrict__ row_ptr, float* __restrict__ dis,
        int* __restrict__ csr_col, int E) {
    __shared__ int pk[CAP];
    __shared__ int csr_lds[CAP];
    __shared__ int deg_loc[RPB];
    __shared__ int scan_loc[RPB];
    __shared__ int cur_loc[RPB];
    int b = blockIdx.x;
    int t = threadIdx.x;
    int start = slot_off[b * NBLK_B];
    int end = slot_off[(b + 1) * NBLK_B];   // b=NB-1 reads slot_off[CNT_N]=E
    int cnt = end - start;
    bool fits = (cnt <= CAP);

    if (t < RPB) deg_loc[t] = 0;
    if (fits) {
        for (int i = t; i < cnt; i += 256) pk[i] = pairs[start + i];
    }
    __syncthreads();
    for (int i = t; i < cnt; i += 256) {
        int p = fits ? pk[i] : pairs[start + i];
        atomicAdd(&deg_loc[p >> 17], 1);
    }
    __syncthreads();
    int d = (t < RPB) ? deg_loc[t] : 0;
    if (t < RPB) scan_loc[t] = d;
    __syncthreads();
    for (int off = 1; off < RPB; off <<= 1) {
        int v = (t < RPB && t >= off) ? scan_loc[t - off] : 0;
        __syncthreads();
        if (t < RPB) scan_loc[t] += v;
        __syncthreads();
    }
    if (t < RPB) {
        int exc = scan_loc[t] - d;
        cur_loc[t] = exc;
        int rg = b * RPB + t;
        if (rg < N_NODES) {
            row_ptr[rg] = start + exc;
            dis[rg] = (d > 0) ? (float)(1.0 / sqrt((double)d)) : 0.0f;
        }
    }
    __syncthreads();
    // place BYTE OFFSETS (col * DIM * 2 = col<<7) by row within the bucket
    for (int i = t; i < cnt; i += 256) {
        int p = fits ? pk[i] : pairs[start + i];
        int pos = atomicAdd(&cur_loc[p >> 17], 1);
        int c = (p & 0x1FFFF) << 7;
        if (fits) csr_lds[pos] = c;
        else      csr_col[start + pos] = c;
    }
    __syncthreads();
    if (fits) {
        for (int i = t; i < cnt; i += 256) csr_col[start + i] = csr_lds[i];
    }
    if (b == NB_BUCKETS - 1 && t == 0) row_ptr[N_NODES] = E;
}

// Grid-stride, two nodes per wave (lanes 0-31 / 32-63). Within a node:
// 4 groups of 8 lanes; group g handles edges start+g, +4, ... Each group
// loads one full fp16 row (128B). Rotated software pipeline: csr offsets for
// iteration i+1 are loaded (branch-free, min-clamped) while iteration i's row
// loads are in flight. Normal cached loads for csr_col (64B line reused ~16x
// per wave -- round-10 lesson: never non-temporal). v_dot2_f32_f16 accumulate;
// cross-group reduce via shfl_xor(8,16).
// MODE 0/1: write x_new = fp16(acc * dis^2)
// MODE 2 (last layer, fused combine): out = 0.25*(embh + x1 + x2 + acc*dis^2)
template <int MODE>
__global__ void gather_kernel(const int* __restrict__ row_ptr, const int* __restrict__ csr_col,
                              const float* __restrict__ dis,
                              const ushort_t* __restrict__ x_old, ushort_t* __restrict__ x_new,
                              const ushort_t* __restrict__ e0, const ushort_t* __restrict__ x1,
                              const ushort_t* __restrict__ x2, float* __restrict__ out,
                              int Npair) {
    int lane = threadIdx.x & 63;
    int sub = lane >> 5;   // which node of the pair
    int l5 = lane & 31;
    int g = l5 >> 3;       // edge-group 0..3 within node
    int l = l5 & 7;        // lane within group: owns dims 8l..8l+7
    int lb = l * 16;       // lane byte offset within a 128B row
    const char* xb = (const char*)x_old;

    int wave0 = (int)((blockIdx.x * (size_t)blockDim.x + threadIdx.x) >> 6);
    int nwaves = (int)(((size_t)gridDim.x * blockDim.x) >> 6);

    for (int wid = wave0; wid < Npair; wid += nwaves) {
        int node = wid * 2 + sub;
        int start = row_ptr[node];
        int end = row_ptr[node + 1];

        float acc[8];
        #pragma unroll
        for (int k = 0; k < 8; ++k) acc[k] = 0.f;

        int e = start + g;
        if (e < end) {
            int o0 = csr_col[e];
            int o1 = (e + 4 < end) ? csr_col[e + 4] : 0;
            while (e + 4 < end) {
                uint4 v0 = *reinterpret_cast<const uint4*>(xb + o0 + lb);
                uint4 v1 = *reinterpret_cast<const uint4*>(xb + o1 + lb);
                o0 = csr_col[min(e + 8, N_EDGES - 1)];
                o1 = csr_col[min(e + 12, N_EDGES - 1)];
                dacc4(acc, v0); dacc4(acc, v1);
                e += 8;
            }
            if (e < end) {   // tail: o0 already holds csr_col[e]
                uint4 v0 = *reinterpret_cast<const uint4*>(xb + o0 + lb);
                dacc4(acc, v0);
            }
        }

        #pragma unroll
        for (int off = 8; off <= 16; off <<= 1) {
            #pragma unroll
            for (int k = 0; k < 8; ++k) acc[k] += __shfl_xor(acc[k], off, 64);
        }

        if (g == 0) {
            float s = dis[node];
            float s2 = s * s;
            if (MODE != 2) {
                uint4 w;
                w.x = f2h(acc[0] * s2) | (f2h(acc[1] * s2) << 16);
                w.y = f2h(acc[2] * s2) | (f2h(acc[3] * s2) << 16);
                w.z = f2h(acc[4] * s2) | (f2h(acc[5] * s2) << 16);
                w.w = f2h(acc[6] * s2) | (f2h(acc[7] * s2) << 16);
                *reinterpret_cast<uint4*>(&x_new[(size_t)node * DIM + l * 8]) = w;
            } else {
                size_t ob = (size_t)node * (DIM * 2) + lb;
                uint4 ea  = *reinterpret_cast<const uint4*>((const char*)e0 + ob);
                uint4 u1  = *reinterpret_cast<const uint4*>((const char*)x1 + ob);
                uint4 u2  = *reinterpret_cast<const uint4*>((const char*)x2 + ob);
                float4 r0, r1;
                r0.x = (hlo(ea.x) + hlo(u1.x) + hlo(u2.x) + acc[0] * s2) * 0.25f;
                r0.y = (hhi(ea.x) + hhi(u1.x) + hhi(u2.x) + acc[1] * s2) * 0.25f;
                r0.z = (hlo(ea.y) + hlo(u1.y) + hlo(u2.y) + acc[2] * s2) * 0.25f;
                r0.w = (hhi(ea.y) + hhi(u1.y) + hhi(u2.y) + acc[3] * s2) * 0.25f;
                r1.x = (hlo(ea.z) + hlo(u1.z) + hlo(u2.z) + acc[4] * s2) * 0.25f;
                r1.y = (hhi(ea.z) + hhi(u1.z) + hhi(u2.z) + acc[5] * s2) * 0.25f;
                r1.z = (hlo(ea.w) + hlo(u1.w) + hlo(u2.w) + acc[6] * s2) * 0.25f;
                r1.w = (hhi(ea.w) + hhi(u1.w) + hhi(u2.w) + acc[7] * s2) * 0.25f;
                size_t oo = (size_t)node * DIM + l * 8;
                *reinterpret_cast<float4*>(&out[oo]) = r0;
                *reinterpret_cast<float4*>(&out[oo + 4]) = r1;
            }
        }
    }
}

extern "C" void kernel_launch(void* const* d_in, const int* in_sizes, int n_in,
                              void* d_out, int out_size, void* d_ws, size_t ws_size,
                              hipStream_t stream) {
    const int* edge = (const int*)d_in[0];       // (2, E) int32
    const int* row = edge;
    const int* col = edge + N_EDGES;
    const float* emb = (const float*)d_in[1];    // (N, 64) f32
    float* out = (float*)d_out;                  // (N, 64) f32

    char* ws = (char*)d_ws;
    size_t off = 0;
    auto alloc = [&](size_t bytes) {
        char* p = ws + off;
        off += (bytes + 255) & ~(size_t)255;
        return p;
    };
    int*      row_ptr  = (int*)alloc(((size_t)N_NODES + 1) * sizeof(int));
    float*    dis      = (float*)alloc((size_t)N_NODES * sizeof(float));
    int*      cnt      = (int*)alloc((size_t)CNT_N * sizeof(int));
    int*      slot_off = (int*)alloc(((size_t)CNT_N + 1) * sizeof(int));
    int*      csr_col  = (int*)alloc((size_t)N_EDGES * sizeof(int));
    ushort_t* embh     = (ushort_t*)alloc((size_t)N_NODES * DIM * sizeof(ushort_t));
    ushort_t* x1       = (ushort_t*)alloc((size_t)N_NODES * DIM * sizeof(ushort_t));
    ushort_t* x2       = (ushort_t*)alloc((size_t)N_NODES * DIM * sizeof(ushort_t));
    // pairs (5MB) aliases x2 (12.8MB): pairs dead after bucket_csr_kernel,
    // x2 first written by the second gather (later) -> lifetimes disjoint.
    int*      pairs    = (int*)x2;

    const int gather_blocks = 2048;   // 8 blocks/CU, persistent grid-stride waves
    const int chunk = (CNT_N + SCAN_BLOCKS - 1) / SCAN_BLOCKS;   // 391 exactly
    const int n8 = N_NODES * DIM / 8;

    // CSR build via 2-level bucket sort: 4 launches (was 6; no grid.sync --
    // round-12 lesson: a kernel launch is the cheap grid-wide barrier)
    conv_hist_kernel<<<NBLK_B + (n8 + 255) / 256, 256, 0, stream>>>(emb, embh, n8, row, cnt, N_EDGES);
    scan_fused_kernel<<<SCAN_BLOCKS, SCAN_BLOCKS, 0, stream>>>(cnt, slot_off, CNT_N, chunk);
    bucket_scatter_kernel<<<NBLK_B, 256, 0, stream>>>(row, col, slot_off, pairs, N_EDGES);
    bucket_csr_kernel<<<NB_BUCKETS, 256, 0, stream>>>(slot_off, pairs, row_ptr, dis, csr_col, N_EDGES);

    // 3 propagate layers (fp16 storage, f32 accumulate via v_dot2_f32_f16);
    // layer 3 fuses the final combine: out = 0.25*(emb + x1 + x2 + x3)
    gather_kernel<0><<<gather_blocks, 256, 0, stream>>>(row_ptr, csr_col, dis, embh, x1,
                                                        nullptr, nullptr, nullptr, nullptr, N_NODES / 2);
    gather_kernel<1><<<gather_blocks, 256, 0, stream>>>(row_ptr, csr_col, dis, x1, x2,
                                                        nullptr, nullptr, nullptr, nullptr, N_NODES / 2);
    gather_kernel<2><<<gather_blocks, 256, 0, stream>>>(row_ptr, csr_col, dis, x2, nullptr,
                                                        embh, x1, x2, out, N_NODES / 2);
}

// Round 14
// 131.783 us; speedup vs baseline: 2.8152x; 1.4151x over previous
//
#include <hip/hip_runtime.h>
#include <math.h>

#define N_NODES 100000
#define DIM 64
#define N_EDGES 1250000
#define SCAN_BLOCKS 256
#define RPB 128                                   // rows per bucket (row>>7)
#define NB_BUCKETS ((N_NODES + RPB - 1) / RPB)    // 782
#define NBLK_B 128                                // blocks in hist/scatter pass
#define CNT_N (NB_BUCKETS * NBLK_B)               // 100096 = 391*256
#define CAP 2048                                  // max edges per bucket (mean 1600)

typedef unsigned short ushort_t;
typedef unsigned int uint_t;
typedef _Float16 h2 __attribute__((ext_vector_type(2)));

// fp16 (storage) <-> f32 (compute) helpers
__device__ __forceinline__ float hlo(uint_t u) {
    return (float)__builtin_bit_cast(_Float16, (ushort_t)(u & 0xFFFFu));
}
__device__ __forceinline__ float hhi(uint_t u) {
    return (float)__builtin_bit_cast(_Float16, (ushort_t)(u >> 16));
}
__device__ __forceinline__ uint_t f2h(float f) {   // RTNE via v_cvt_f16_f32
    return (uint_t)__builtin_bit_cast(ushort_t, (_Float16)f);
}

// acc two fp16 lanes of a dword into two f32 accumulators via v_dot2_f32_f16
__device__ __forceinline__ void dacc(float& a0, float& a1, uint_t u) {
#if __has_builtin(__builtin_amdgcn_fdot2)
    h2 h = __builtin_bit_cast(h2, u);
    const h2 e0 = {(_Float16)1.0f, (_Float16)0.0f};
    const h2 e1 = {(_Float16)0.0f, (_Float16)1.0f};
    a0 = __builtin_amdgcn_fdot2(h, e0, a0, false);
    a1 = __builtin_amdgcn_fdot2(h, e1, a1, false);
#else
    a0 += hlo(u);
    a1 += hhi(u);
#endif
}

__device__ __forceinline__ void dacc4(float* acc, uint4 v) {
    dacc(acc[0], acc[1], v.x); dacc(acc[2], acc[3], v.y);
    dacc(acc[4], acc[5], v.z); dacc(acc[6], acc[7], v.w);
}

// ---- fused: blocks [0,NBLK_B) = bucket histogram; rest = emb->fp16 conv ---
__global__ void conv_hist_kernel(const float* __restrict__ emb, ushort_t* __restrict__ embh,
                                 int n8, const int* __restrict__ row,
                                 int* __restrict__ cnt, int E) {
    __shared__ int h[NB_BUCKETS];
    if (blockIdx.x < NBLK_B) {
        for (int i = threadIdx.x; i < NB_BUCKETS; i += blockDim.x) h[i] = 0;
        __syncthreads();
        int blk = blockIdx.x;
        int per = (E + NBLK_B - 1) / NBLK_B;
        int lo = blk * per, hi = min(lo + per, E);
        for (int e = lo + (int)threadIdx.x; e < hi; e += blockDim.x)
            atomicAdd(&h[row[e] >> 7], 1);
        __syncthreads();
        for (int b = threadIdx.x; b < NB_BUCKETS; b += blockDim.x)
            cnt[b * NBLK_B + blk] = h[b];   // bucket-major: scan order = slot order
    } else {
        int i = (blockIdx.x - NBLK_B) * blockDim.x + threadIdx.x;
        if (i < n8) {
            float4 a = reinterpret_cast<const float4*>(emb)[2 * i];
            float4 b = reinterpret_cast<const float4*>(emb)[2 * i + 1];
            uint4 w;
            w.x = f2h(a.x) | (f2h(a.y) << 16);
            w.y = f2h(a.z) | (f2h(a.w) << 16);
            w.z = f2h(b.x) | (f2h(b.y) << 16);
            w.w = f2h(b.z) | (f2h(b.w) << 16);
            reinterpret_cast<uint4*>(embh)[i] = w;
        }
    }
}

// ---- scan stage 1: per-chunk partial sums (coalesced block-strided reads) --
__global__ void partial_kernel(const int* __restrict__ in, int* __restrict__ blocksum,
                               int N, int chunk) {
    __shared__ int sh[256];
    int b = blockIdx.x;
    int lo = b * chunk, hi = min(lo + chunk, N);
    int s = 0;
    for (int i = lo + (int)threadIdx.x; i < hi; i += 256) s += in[i];
    sh[threadIdx.x] = s;
    __syncthreads();
    for (int off = 128; off > 0; off >>= 1) {
        if ((int)threadIdx.x < off) sh[threadIdx.x] += sh[threadIdx.x + off];
        __syncthreads();
    }
    if (threadIdx.x == 0) blocksum[b] = sh[0];
}

// ---- scan stage 2 (fused): redundant 256-int blocksum scan + tile-scan emit.
// The redundant part is only 1KB of coalesced reads + an LDS scan per block --
// cheap (round-13 lesson: redundant-scan is only free when the redundant part
// is tiny; 400KB/block of uncoalesced reads was 63us).
__global__ void __launch_bounds__(256) scan_emit_kernel(
        const int* __restrict__ in, const int* __restrict__ blocksum,
        int* __restrict__ out, int N, int chunk) {
    __shared__ int sh[SCAN_BLOCKS];
    int t = threadIdx.x;
    int b = blockIdx.x;
    // redundant exclusive scan of the 256 blocksums
    int v = blocksum[t];
    sh[t] = v;
    __syncthreads();
    for (int off = 1; off < SCAN_BLOCKS; off <<= 1) {
        int u = (t >= off) ? sh[t - off] : 0;
        __syncthreads();
        sh[t] += u;
        __syncthreads();
    }
    int running = (b > 0) ? sh[b - 1] : 0;   // own exclusive base
    int total = sh[SCAN_BLOCKS - 1];
    __syncthreads();
    // tile-scan own chunk -> out
    int lo = b * chunk, hi = min(lo + chunk, N);
    for (int base = lo; base < hi; base += 256) {
        int i = base + t;
        int d = (i < hi) ? in[i] : 0;
        sh[t] = d;
        __syncthreads();
        for (int off = 1; off < 256; off <<= 1) {
            int u = (t >= off) ? sh[t - off] : 0;
            __syncthreads();
            sh[t] += u;
            __syncthreads();
        }
        if (i < hi) out[i] = running + (sh[t] - d);
        running += sh[255];
        __syncthreads();
    }
    if (b == 0 && t == 0) out[N] = total;   // = E
}

// ---- bucket pass 2: scatter packed edges into per-(bucket,block) slots ----
__global__ void bucket_scatter_kernel(const int* __restrict__ row, const int* __restrict__ col,
                                      const int* __restrict__ slot_off,
                                      int* __restrict__ pairs, int E) {
    __shared__ int cur[NB_BUCKETS];
    int blk = blockIdx.x;
    for (int b = threadIdx.x; b < NB_BUCKETS; b += blockDim.x)
        cur[b] = slot_off[b * NBLK_B + blk];
    __syncthreads();
    int per = (E + (int)gridDim.x - 1) / (int)gridDim.x;
    int lo = blk * per, hi = min(lo + per, E);
    for (int e = lo + (int)threadIdx.x; e < hi; e += blockDim.x) {
        int r = row[e], c = col[e];
        int pos = atomicAdd(&cur[r >> 7], 1);
        pairs[pos] = ((r & (RPB - 1)) << 17) | c;
    }
}

// ---- bucket pass 3: one block per bucket -> row_ptr, dis, csr (byte offs) --
__global__ void __launch_bounds__(256) bucket_csr_kernel(
        const int* __restrict__ slot_off, const int* __restrict__ pairs,
        int* __restrict__ row_ptr, float* __restrict__ dis,
        int* __restrict__ csr_col, int E) {
    __shared__ int pk[CAP];
    __shared__ int csr_lds[CAP];
    __shared__ int deg_loc[RPB];
    __shared__ int scan_loc[RPB];
    __shared__ int cur_loc[RPB];
    int b = blockIdx.x;
    int t = threadIdx.x;
    int start = slot_off[b * NBLK_B];
    int end = slot_off[(b + 1) * NBLK_B];   // b=NB-1 reads slot_off[CNT_N]=E
    int cnt = end - start;
    bool fits = (cnt <= CAP);

    if (t < RPB) deg_loc[t] = 0;
    if (fits) {
        for (int i = t; i < cnt; i += 256) pk[i] = pairs[start + i];
    }
    __syncthreads();
    for (int i = t; i < cnt; i += 256) {
        int p = fits ? pk[i] : pairs[start + i];
        atomicAdd(&deg_loc[p >> 17], 1);
    }
    __syncthreads();
    int d = (t < RPB) ? deg_loc[t] : 0;
    if (t < RPB) scan_loc[t] = d;
    __syncthreads();
    for (int off = 1; off < RPB; off <<= 1) {
        int v = (t < RPB && t >= off) ? scan_loc[t - off] : 0;
        __syncthreads();
        if (t < RPB) scan_loc[t] += v;
        __syncthreads();
    }
    if (t < RPB) {
        int exc = scan_loc[t] - d;
        cur_loc[t] = exc;
        int rg = b * RPB + t;
        if (rg < N_NODES) {
            row_ptr[rg] = start + exc;
            dis[rg] = (d > 0) ? (float)(1.0 / sqrt((double)d)) : 0.0f;
        }
    }
    __syncthreads();
    // place BYTE OFFSETS (col * DIM * 2 = col<<7) by row within the bucket
    for (int i = t; i < cnt; i += 256) {
        int p = fits ? pk[i] : pairs[start + i];
        int pos = atomicAdd(&cur_loc[p >> 17], 1);
        int c = (p & 0x1FFFF) << 7;
        if (fits) csr_lds[pos] = c;
        else      csr_col[start + pos] = c;
    }
    __syncthreads();
    if (fits) {
        for (int i = t; i < cnt; i += 256) csr_col[start + i] = csr_lds[i];
    }
    if (b == NB_BUCKETS - 1 && t == 0) row_ptr[N_NODES] = E;
}

// Grid-stride, two nodes per wave (lanes 0-31 / 32-63). Within a node:
// 4 groups of 8 lanes; group g handles edges start+g, +4, ... Each group
// loads one full fp16 row (128B). Rotated software pipeline: csr offsets for
// iteration i+1 are loaded (branch-free, min-clamped) while iteration i's row
// loads are in flight. Normal cached loads for csr_col (64B line reused ~16x
// per wave -- round-10 lesson: never non-temporal). v_dot2_f32_f16 accumulate;
// cross-group reduce via shfl_xor(8,16).
// MODE 0/1: write x_new = fp16(acc * dis^2)
// MODE 2 (last layer, fused combine): out = 0.25*(embh + x1 + x2 + acc*dis^2)
template <int MODE>
__global__ void gather_kernel(const int* __restrict__ row_ptr, const int* __restrict__ csr_col,
                              const float* __restrict__ dis,
                              const ushort_t* __restrict__ x_old, ushort_t* __restrict__ x_new,
                              const ushort_t* __restrict__ e0, const ushort_t* __restrict__ x1,
                              const ushort_t* __restrict__ x2, float* __restrict__ out,
                              int Npair) {
    int lane = threadIdx.x & 63;
    int sub = lane >> 5;   // which node of the pair
    int l5 = lane & 31;
    int g = l5 >> 3;       // edge-group 0..3 within node
    int l = l5 & 7;        // lane within group: owns dims 8l..8l+7
    int lb = l * 16;       // lane byte offset within a 128B row
    const char* xb = (const char*)x_old;

    int wave0 = (int)((blockIdx.x * (size_t)blockDim.x + threadIdx.x) >> 6);
    int nwaves = (int)(((size_t)gridDim.x * blockDim.x) >> 6);

    for (int wid = wave0; wid < Npair; wid += nwaves) {
        int node = wid * 2 + sub;
        int start = row_ptr[node];
        int end = row_ptr[node + 1];

        float acc[8];
        #pragma unroll
        for (int k = 0; k < 8; ++k) acc[k] = 0.f;

        int e = start + g;
        if (e < end) {
            int o0 = csr_col[e];
            int o1 = (e + 4 < end) ? csr_col[e + 4] : 0;
            while (e + 4 < end) {
                uint4 v0 = *reinterpret_cast<const uint4*>(xb + o0 + lb);
                uint4 v1 = *reinterpret_cast<const uint4*>(xb + o1 + lb);
                o0 = csr_col[min(e + 8, N_EDGES - 1)];
                o1 = csr_col[min(e + 12, N_EDGES - 1)];
                dacc4(acc, v0); dacc4(acc, v1);
                e += 8;
            }
            if (e < end) {   // tail: o0 already holds csr_col[e]
                uint4 v0 = *reinterpret_cast<const uint4*>(xb + o0 + lb);
                dacc4(acc, v0);
            }
        }

        #pragma unroll
        for (int off = 8; off <= 16; off <<= 1) {
            #pragma unroll
            for (int k = 0; k < 8; ++k) acc[k] += __shfl_xor(acc[k], off, 64);
        }

        if (g == 0) {
            float s = dis[node];
            float s2 = s * s;
            if (MODE != 2) {
                uint4 w;
                w.x = f2h(acc[0] * s2) | (f2h(acc[1] * s2) << 16);
                w.y = f2h(acc[2] * s2) | (f2h(acc[3] * s2) << 16);
                w.z = f2h(acc[4] * s2) | (f2h(acc[5] * s2) << 16);
                w.w = f2h(acc[6] * s2) | (f2h(acc[7] * s2) << 16);
                *reinterpret_cast<uint4*>(&x_new[(size_t)node * DIM + l * 8]) = w;
            } else {
                size_t ob = (size_t)node * (DIM * 2) + lb;
                uint4 ea  = *reinterpret_cast<const uint4*>((const char*)e0 + ob);
                uint4 u1  = *reinterpret_cast<const uint4*>((const char*)x1 + ob);
                uint4 u2  = *reinterpret_cast<const uint4*>((const char*)x2 + ob);
                float4 r0, r1;
                r0.x = (hlo(ea.x) + hlo(u1.x) + hlo(u2.x) + acc[0] * s2) * 0.25f;
                r0.y = (hhi(ea.x) + hhi(u1.x) + hhi(u2.x) + acc[1] * s2) * 0.25f;
                r0.z = (hlo(ea.y) + hlo(u1.y) + hlo(u2.y) + acc[2] * s2) * 0.25f;
                r0.w = (hhi(ea.y) + hhi(u1.y) + hhi(u2.y) + acc[3] * s2) * 0.25f;
                r1.x = (hlo(ea.z) + hlo(u1.z) + hlo(u2.z) + acc[4] * s2) * 0.25f;
                r1.y = (hhi(ea.z) + hhi(u1.z) + hhi(u2.z) + acc[5] * s2) * 0.25f;
                r1.z = (hlo(ea.w) + hlo(u1.w) + hlo(u2.w) + acc[6] * s2) * 0.25f;
                r1.w = (hhi(ea.w) + hhi(u1.w) + hhi(u2.w) + acc[7] * s2) * 0.25f;
                size_t oo = (size_t)node * DIM + l * 8;
                *reinterpret_cast<float4*>(&out[oo]) = r0;
                *reinterpret_cast<float4*>(&out[oo + 4]) = r1;
            }
        }
    }
}

extern "C" void kernel_launch(void* const* d_in, const int* in_sizes, int n_in,
                              void* d_out, int out_size, void* d_ws, size_t ws_size,
                              hipStream_t stream) {
    const int* edge = (const int*)d_in[0];       // (2, E) int32
    const int* row = edge;
    const int* col = edge + N_EDGES;
    const float* emb = (const float*)d_in[1];    // (N, 64) f32
    float* out = (float*)d_out;                  // (N, 64) f32

    char* ws = (char*)d_ws;
    size_t off = 0;
    auto alloc = [&](size_t bytes) {
        char* p = ws + off;
        off += (bytes + 255) & ~(size_t)255;
        return p;
    };
    int*      row_ptr  = (int*)alloc(((size_t)N_NODES + 1) * sizeof(int));
    float*    dis      = (float*)alloc((size_t)N_NODES * sizeof(float));
    int*      blocksum = (int*)alloc((size_t)SCAN_BLOCKS * sizeof(int));
    int*      cnt      = (int*)alloc((size_t)CNT_N * sizeof(int));
    int*      slot_off = (int*)alloc(((size_t)CNT_N + 1) * sizeof(int));
    int*      csr_col  = (int*)alloc((size_t)N_EDGES * sizeof(int));
    ushort_t* embh     = (ushort_t*)alloc((size_t)N_NODES * DIM * sizeof(ushort_t));
    ushort_t* x1       = (ushort_t*)alloc((size_t)N_NODES * DIM * sizeof(ushort_t));
    ushort_t* x2       = (ushort_t*)alloc((size_t)N_NODES * DIM * sizeof(ushort_t));
    // pairs (5MB) aliases x2 (12.8MB): pairs dead after bucket_csr_kernel,
    // x2 first written by the second gather (later) -> lifetimes disjoint.
    int*      pairs    = (int*)x2;

    const int gather_blocks = 2048;   // 8 blocks/CU, persistent grid-stride waves
    const int chunk = (CNT_N + SCAN_BLOCKS - 1) / SCAN_BLOCKS;   // 391 exactly
    const int n8 = N_NODES * DIM / 8;

    // CSR build via 2-level bucket sort: 5 launches (scan_small folded into
    // scan_emit via a 256-int redundant scan; round-12/13 lessons: kernel
    // launches are the cheap barrier, redundancy only when tiny+coalesced)
    conv_hist_kernel<<<NBLK_B + (n8 + 255) / 256, 256, 0, stream>>>(emb, embh, n8, row, cnt, N_EDGES);
    partial_kernel<<<SCAN_BLOCKS, 256, 0, stream>>>(cnt, blocksum, CNT_N, chunk);
    scan_emit_kernel<<<SCAN_BLOCKS, 256, 0, stream>>>(cnt, blocksum, slot_off, CNT_N, chunk);
    bucket_scatter_kernel<<<NBLK_B, 256, 0, stream>>>(row, col, slot_off, pairs, N_EDGES);
    bucket_csr_kernel<<<NB_BUCKETS, 256, 0, stream>>>(slot_off, pairs, row_ptr, dis, csr_col, N_EDGES);

    // 3 propagate layers (fp16 storage, f32 accumulate via v_dot2_f32_f16);
    // layer 3 fuses the final combine: out = 0.25*(emb + x1 + x2 + x3)
    gather_kernel<0><<<gather_blocks, 256, 0, stream>>>(row_ptr, csr_col, dis, embh, x1,
                                                        nullptr, nullptr, nullptr, nullptr, N_NODES / 2);
    gather_kernel<1><<<gather_blocks, 256, 0, stream>>>(row_ptr, csr_col, dis, x1, x2,
                                                        nullptr, nullptr, nullptr, nullptr, N_NODES / 2);
    gather_kernel<2><<<gather_blocks, 256, 0, stream>>>(row_ptr, csr_col, dis, x2, nullptr,
                                                        embh, x1, x2, out, N_NODES / 2);
}